// Round 15
// baseline (1683.727 us; speedup 1.0000x reference)
//
#include <hip/hip_runtime.h>
#include <math.h>

#define NB 128
#define TT 128
#define HD 1024
#define FH 4096
#define QB 16            // qk contention-spread buckets
#define QSLOT (QB * 2048)

typedef __attribute__((ext_vector_type(8))) short short8v;
typedef __attribute__((ext_vector_type(4))) float float4v;

__device__ __forceinline__ ushort f2b(float f) {
    union { float f; unsigned u; } v; v.f = f;
    unsigned r = (v.u + 0x7fffu + ((v.u >> 16) & 1u)) >> 16;
    return (ushort)r;
}
__device__ __forceinline__ float b2f(ushort u) {
    union { unsigned u; float f; } v; v.u = ((unsigned)u) << 16;
    return v.f;
}
__device__ __forceinline__ float sigm(float x) {
    return __builtin_amdgcn_rcpf(1.f + __expf(-x));
}
__device__ __forceinline__ float tanh_fast(float x) {
    return 1.f - 2.f * __builtin_amdgcn_rcpf(1.f + __expf(2.f * x));
}
__device__ __forceinline__ void gll16(const void* g, void* l) {
    __builtin_amdgcn_global_load_lds(
        (const __attribute__((address_space(1))) void*)g,
        (__attribute__((address_space(3))) void*)l,
        16, 0, 0);
}
// XOR chunk swizzle within a 16-chunk (256B) row; involution in low 3 bits.
__device__ __forceinline__ int swz(int c, int r) {
    return (c & 8) | ((c & 7) ^ (r & 7));
}

// ---------------------------------------------------------------------------
// x fp32 -> bf16 ([N][T][D] preserved)
__global__ __launch_bounds__(256) void cvt_x(const float* __restrict__ x,
                                             ushort* __restrict__ xb) {
    size_t i = (size_t)blockIdx.x * 256 + threadIdx.x;
    const float4* p = (const float4*)x + i * 2;
    float4 va = p[0], vb = p[1];
    union { ushort u[8]; uint4 v; } o;
    o.u[0] = f2b(va.x); o.u[1] = f2b(va.y); o.u[2] = f2b(va.z); o.u[3] = f2b(va.w);
    o.u[4] = f2b(vb.x); o.u[5] = f2b(vb.y); o.u[6] = f2b(vb.z); o.u[7] = f2b(vb.w);
    ((uint4*)xb)[i] = o.v;
}

// ---------------------------------------------------------------------------
// WT layout: [WxT (4096x1024)] [WhT (4096x1024)] [WatT (4096x1024)], bf16.
__global__ __launch_bounds__(256) void build_wt(const float* __restrict__ Wx,
                                                const float* __restrict__ Wh,
                                                const float* __restrict__ Wattn,
                                                ushort* __restrict__ WT) {
    __shared__ ushort Ls[64][65];
    int k0 = blockIdx.x * 64, n0 = blockIdx.y * 64;
    const float* W; int m;
    if (k0 < 1024)      { W = Wx;    m = 0; }
    else if (k0 < 2048) { W = Wh;    m = 1; }
    else                { W = Wattn; m = 2; }
    const int kk0 = k0 - m * 1024;
    ushort* dstm = WT + (size_t)m * FH * 1024;
    int t = threadIdx.x;
    int cc = t & 63, r4 = t >> 6;
#pragma unroll
    for (int i = 0; i < 16; ++i) {
        int r = i * 4 + r4;
        Ls[r][cc] = f2b(W[(size_t)(kk0 + r) * FH + n0 + cc]);
    }
    __syncthreads();
#pragma unroll
    for (int i = 0; i < 16; ++i) {
        int nn = i * 4 + r4;
        dstm[(size_t)(n0 + nn) * 1024 + kk0 + cc] = Ls[cc][nn];
    }
}

// ---------------------------------------------------------------------------
// init: h0=c0=meanpool(A); Ab16 = bf16(A); qk0 bucket0 = sum_h h0*A,
// buckets 1..15 zero; qk1 all zero.
__global__ __launch_bounds__(256) void init_kernel(
    const float* __restrict__ Aflat, float* __restrict__ cbuf,
    ushort* __restrict__ h0buf, ushort* __restrict__ Ab16,
    float* __restrict__ qk0, float* __restrict__ qk1)
{
    __shared__ float red[4][16];
    const int n = blockIdx.x, tid = threadIdx.x;
    const int wv = tid >> 6, l = tid & 63;
    float p[16];
#pragma unroll
    for (int k = 0; k < 16; ++k) p[k] = 0.f;
#pragma unroll
    for (int u = 0; u < 4; ++u) {
        const int h = tid + u * 256;
        const size_t idx = (size_t)n * 1024 + h;
        const float4* a4 = (const float4*)(Aflat + idx * 16);
        float ar[16];
#pragma unroll
        for (int q = 0; q < 4; ++q) {
            float4 v = a4[q];
            ar[q*4+0]=v.x; ar[q*4+1]=v.y; ar[q*4+2]=v.z; ar[q*4+3]=v.w;
        }
        union { ushort us[16]; uint4 v[2]; } ob;
#pragma unroll
        for (int k = 0; k < 16; ++k) ob.us[k] = f2b(ar[k]);
        uint4* dst = (uint4*)(Ab16 + idx * 16);
        dst[0] = ob.v[0]; dst[1] = ob.v[1];

        float s = 0.f;
#pragma unroll
        for (int k = 0; k < 16; ++k) s += ar[k];
        float hv = s * 0.0625f;
        cbuf[idx] = hv;
        h0buf[idx] = f2b(hv);
#pragma unroll
        for (int k = 0; k < 16; ++k) p[k] += hv * ar[k];
    }
#pragma unroll
    for (int k = 0; k < 16; ++k) {
        float v = p[k];
        v += __shfl_xor(v, 32); v += __shfl_xor(v, 16); v += __shfl_xor(v, 8);
        v += __shfl_xor(v, 4);  v += __shfl_xor(v, 2);  v += __shfl_xor(v, 1);
        p[k] = v;
    }
    if (l == 0) {
#pragma unroll
        for (int k = 0; k < 16; ++k) red[wv][k] = p[k];
    }
    __syncthreads();
    if (tid < 16) {
        float val = red[0][tid] + red[1][tid] + red[2][tid] + red[3][tid];
#pragma unroll
        for (int bkt = 0; bkt < QB; ++bkt) {
            qk0[bkt * 2048 + n * 16 + tid] = (bkt == 0) ? val : 0.f;
            qk1[bkt * 2048 + n * 16 + tid] = 0.f;
        }
    }
}

// ---------------------------------------------------------------------------
// P2[n][j][k] = sum_h A[n][h][k] * Wattn[h][j]; 4-n batched per block.
__global__ __launch_bounds__(256) void p_gemm(
    const ushort* __restrict__ Ab16,    // [128][1024][16]
    const ushort* __restrict__ WatT,    // [4096][1024]
    ushort* __restrict__ P2)            // [128][4096][16] bf16
{
    __shared__ ushort ALDS[4 * 16 * 72];
    __shared__ ushort Bs[256 * 64];
    const int tid = threadIdx.x;
    const int wv = tid >> 6, l = tid & 63;
    const int lr = l & 15, g = l >> 4;
    const int jt = blockIdx.x, n0 = blockIdx.y * 4;
    const int snn = tid >> 6, shl = tid & 63;

    float4v acc[4][4];
#pragma unroll
    for (int i = 0; i < 4; ++i)
#pragma unroll
        for (int j = 0; j < 4; ++j) acc[i][j] = (float4v){0.f, 0.f, 0.f, 0.f};

#pragma unroll 1
    for (int kc = 0; kc < 16; ++kc) {
        __syncthreads();
        {
            const ushort* src = Ab16 + ((size_t)(n0 + snn) * 1024 + kc * 64 + shl) * 16;
            union { uint4 v[2]; ushort us[16]; } iv;
            iv.v[0] = *(const uint4*)src;
            iv.v[1] = *(const uint4*)(src + 8);
#pragma unroll
            for (int k = 0; k < 16; ++k)
                ALDS[(snn * 16 + k) * 72 + shl] = iv.us[k];
        }
#pragma unroll
        for (int i = 0; i < 8; ++i) {
            int s = i * 256 + tid;
            int r = s >> 3, c = (s & 7) ^ (r & 7);
            gll16(WatT + (size_t)(jt * 256 + r) * 1024 + kc * 64 + c * 8,
                  &Bs[s * 8]);
        }
        __syncthreads();
#pragma unroll
        for (int sub = 0; sub < 2; ++sub) {
            short8v af[4], bf[4];
#pragma unroll
            for (int nn = 0; nn < 4; ++nn)
                af[nn] = *(const short8v*)&ALDS[(nn * 16 + lr) * 72 + sub * 32 + g * 8];
#pragma unroll
            for (int nf = 0; nf < 4; ++nf) {
                int rb = wv * 64 + nf * 16 + lr;
                bf[nf] = *(const short8v*)&Bs[rb * 64 + (((sub * 4 + g) ^ (rb & 7)) * 8)];
            }
#pragma unroll
            for (int nn = 0; nn < 4; ++nn)
#pragma unroll
                for (int nf = 0; nf < 4; ++nf)
                    acc[nn][nf] = __builtin_amdgcn_mfma_f32_16x16x32_bf16(
                        af[nn], bf[nf], acc[nn][nf], 0, 0, 0);
        }
    }

#pragma unroll
    for (int nn = 0; nn < 4; ++nn)
#pragma unroll
        for (int nf = 0; nf < 4; ++nf) {
            const int j = jt * 256 + wv * 64 + nf * 16 + lr;
            union { ushort u[4]; uint2 v; } o;
#pragma unroll
            for (int jj = 0; jj < 4; ++jj) o.u[jj] = f2b(acc[nn][nf][jj]);
            *(uint2*)&P2[((size_t)(n0 + nn) * FH + j) * 16 + g * 4] = o.v;
        }
}

// ---------------------------------------------------------------------------
// XA[t][n][j] = x[n,t,:] @ Wx.  16384 x 1024 x 4096, BK=64 dbuf, 2 blocks/CU.
// B16A=1: A staged via gll16 from pre-converted xb (bf16 slabs fit L2).
// XCD-chunked bid swizzle: each XCD owns 16 A-slabs, sweeps 32 ntiles.
template <int B16A>
__global__ __launch_bounds__(256) void xa_gemm3(
    const float* __restrict__ x,        // [128][128][1024] fp32 (B16A=0)
    const ushort* __restrict__ xb,      // same, bf16 (B16A=1)
    const ushort* __restrict__ WxT,     // [4096][1024]
    ushort* __restrict__ xab)           // [128t][128n][4096]
{
    __shared__ ushort As[2][128 * 64];
    __shared__ ushort Bs[2][128 * 64];
    const int tid = threadIdx.x;
    const int w = tid >> 6, l = tid & 63;
    const int wm = w >> 1, wn = w & 1;
    const int lr = l & 15, g = l >> 4;

    const int bid = blockIdx.x;
    const int xcd = bid & 7, ii = bid >> 3;
    const int mt = xcd * 16 + (ii & 15);
    const int n0 = (ii >> 4) * 128;

    const float*  Ax  = x  + (size_t)mt * 128 * 1024;
    const ushort* Axb = xb + (size_t)mt * 128 * 1024;
    const ushort* Bb  = WxT + (size_t)n0 * 1024;

#define STAGEA(b, kf)                                                          \
    do {                                                                       \
        if (B16A) {                                                            \
            _Pragma("unroll")                                                  \
            for (int i = 0; i < 4; ++i) {                                      \
                int s = i * 256 + tid;                                         \
                int r = s >> 3, c = s & 7;                                     \
                gll16(Axb + (size_t)r * 1024 + (kf) + (c ^ (r & 7)) * 8,       \
                      &As[b][s * 8]);                                          \
            }                                                                  \
        } else {                                                               \
            _Pragma("unroll")                                                  \
            for (int i = 0; i < 4; ++i) {                                      \
                int u = i * 256 + tid;                                         \
                int r = u >> 3, c = u & 7;                                     \
                const float* s = Ax + (size_t)r * 1024 + (kf) + c * 8;         \
                float4 v0 = *(const float4*)s;                                 \
                float4 v1 = *(const float4*)(s + 4);                           \
                union { ushort us[8]; uint4 v; } o;                            \
                o.us[0]=f2b(v0.x); o.us[1]=f2b(v0.y); o.us[2]=f2b(v0.z);       \
                o.us[3]=f2b(v0.w); o.us[4]=f2b(v1.x); o.us[5]=f2b(v1.y);       \
                o.us[6]=f2b(v1.z); o.us[7]=f2b(v1.w);                          \
                *(uint4*)&As[b][(r * 8 + (c ^ (r & 7))) * 8] = o.v;            \
            }                                                                  \
        }                                                                      \
    } while (0)
#define STAGEB(b, kf)                                                          \
    do {                                                                       \
        _Pragma("unroll")                                                      \
        for (int s2 = 0; s2 < 4; ++s2) {                                       \
            int s = s2 * 256 + tid;                                            \
            int r = s >> 3, c = s & 7;                                         \
            gll16(Bb + (size_t)r * 1024 + (kf) + (c ^ (r & 7)) * 8,            \
                  &Bs[b][s * 8]);                                              \
        }                                                                      \
    } while (0)

    float4v acc[4][4];
#pragma unroll
    for (int i = 0; i < 4; ++i)
#pragma unroll
        for (int j = 0; j < 4; ++j) acc[i][j] = (float4v){0.f, 0.f, 0.f, 0.f};

    STAGEA(0, 0);
    STAGEB(0, 0);
    __syncthreads();
    int buf = 0;
#pragma unroll 1
    for (int kc = 0; kc < 16; ++kc) {
        if (kc < 15) { STAGEA(buf ^ 1, (kc + 1) * 64); STAGEB(buf ^ 1, (kc + 1) * 64); }
        const ushort* Ab = As[buf];
        const ushort* Bbuf = Bs[buf];
#pragma unroll
        for (int sub = 0; sub < 2; ++sub) {
            short8v af[4], bf[4];
#pragma unroll
            for (int mf = 0; mf < 4; ++mf) {
                int ra = wm * 64 + mf * 16 + lr;
                af[mf] = *(const short8v*)&Ab[ra * 64 + (((sub * 4 + g) ^ (ra & 7)) * 8)];
            }
#pragma unroll
            for (int nf = 0; nf < 4; ++nf) {
                int rb = wn * 64 + nf * 16 + lr;
                bf[nf] = *(const short8v*)&Bbuf[rb * 64 + (((sub * 4 + g) ^ (rb & 7)) * 8)];
            }
#pragma unroll
            for (int mf = 0; mf < 4; ++mf)
#pragma unroll
                for (int nf = 0; nf < 4; ++nf)
                    acc[mf][nf] = __builtin_amdgcn_mfma_f32_16x16x32_bf16(
                        af[mf], bf[nf], acc[mf][nf], 0, 0, 0);
        }
        __syncthreads();
        buf ^= 1;
    }
#undef STAGEA
#undef STAGEB

#pragma unroll
    for (int mf = 0; mf < 4; ++mf)
#pragma unroll
        for (int nf = 0; nf < 4; ++nf) {
            const int col = n0 + wn * 64 + nf * 16 + lr;
#pragma unroll
            for (int j = 0; j < 4; ++j) {
                const int rl = wm * 64 + mf * 16 + g * 4 + j;
                xab[((size_t)rl * NB + mt) * FH + col] = f2b(acc[mf][nf][j]);
            }
        }
}

// ---------------------------------------------------------------------------
// Per-step kernel. XAF=1: K=1024 (h @ WhT), counted-vmcnt pipelined K-loop
// (T4, m201 pattern). COMPUTE takes a BUFFER index (0/1) — round-14 bug was
// passing k-chunk indices 2/3 here (OOB LDS reads -> NaN).
template <int XAF>
__global__ __launch_bounds__(256) void step_kernel(
    const ushort* __restrict__ hcur,    // [128][1024] bf16
    ushort* __restrict__ hnext,
    const ushort* __restrict__ xb_t,    // XAF=0: + t*HD, row stride TT*HD
    const ushort* __restrict__ xab_t,   // XAF=1: + t*NB*FH
    const ushort* __restrict__ WxT,     // [4096][1024]
    const ushort* __restrict__ WhT,     // [4096][1024]
    const ushort* __restrict__ P2,      // [128][4096][16]
    const ushort* __restrict__ Ab16,    // [128][1024][16]
    const float* __restrict__ bias,
    float* __restrict__ cbuf,
    const float* __restrict__ qk_cur,   // [QB][2048]
    float* __restrict__ qk_next,
    float* __restrict__ qk_zero,
    float* __restrict__ out_t)          // + t*HD, row stride TT*HD
{
    __shared__ ushort AS[16384];
    __shared__ ushort BS[16384];
    __shared__ float accL[2 * 32 * 33];
    __shared__ float wLDS[32 * 16];

    const int tid = threadIdx.x;
    const int w = tid >> 6, l = tid & 63;
    const int mh = w & 1, kh = w >> 1;
    const int lr = l & 15, g = l >> 4;

    // XCD-chunked swizzle
    const int bid = blockIdx.x;
    const int xcd = bid & 7, ii = bid >> 3;
    const int bx = xcd * 16 + (ii & 15);
    const int my = ii >> 4;
    const int n0 = my * 32;

#define STAGE(b, kc)                                                           \
    do {                                                                       \
        _Pragma("unroll")                                                      \
        for (int i = 0; i < 4; ++i) {                                          \
            int u = i * 256 + tid;                                             \
            int skh = u >> 9, rem = u & 511;                                   \
            int r = rem >> 4, c = rem & 15;                                    \
            int lc = swz(c, r);                                                \
            const ushort* src;                                                 \
            if (XAF == 1)                                                      \
                src = hcur + (size_t)(n0 + r) * 1024 + skh * 512               \
                      + (kc) * 128 + lc * 8;                                   \
            else                                                               \
                src = skh                                                      \
                    ? hcur + (size_t)(n0 + r) * 1024 + (kc) * 128 + lc * 8     \
                    : xb_t + (size_t)(n0 + r) * (TT * HD) + (kc) * 128 + lc * 8;\
            gll16(src, AS + (((b) * 2 + skh) * 512 + rem) * 8);                \
        }                                                                      \
        _Pragma("unroll")                                                      \
        for (int i = 0; i < 4; ++i) {                                          \
            int u = i * 256 + tid;                                             \
            int skh = u >> 9, rem = u & 511;                                   \
            int r = rem >> 4, c = rem & 15;                                    \
            int lc = swz(c, r);                                                \
            int jg = (r >> 3) * 1024 + bx * 8 + (r & 7);                       \
            const ushort* src;                                                 \
            if (XAF == 1)                                                      \
                src = WhT + (size_t)jg * 1024 + skh * 512 + (kc) * 128 + lc * 8;\
            else                                                               \
                src = (skh ? WhT : WxT) + (size_t)jg * 1024                    \
                      + (kc) * 128 + lc * 8;                                   \
            gll16(src, BS + (((b) * 2 + skh) * 512 + rem) * 8);                \
        }                                                                      \
    } while (0)

#define COMPUTE(b)                                                             \
    do {                                                                       \
        const int base_ = ((b) * 2 + kh) * 512;                                \
        const int ra_ = mh * 16 + lr;                                          \
        _Pragma("unroll")                                                      \
        for (int ks = 0; ks < 4; ++ks) {                                       \
            const int c_ = ks * 4 + g;                                         \
            short8v af = *(const short8v*)&AS[(base_ + ra_ * 16 + swz(c_, ra_)) * 8]; \
            _Pragma("unroll")                                                  \
            for (int nf = 0; nf < 2; ++nf) {                                   \
                const int rb_ = nf * 16 + lr;                                  \
                short8v bf = *(const short8v*)&BS[(base_ + rb_ * 16 + swz(c_, rb_)) * 8]; \
                acc[nf] = __builtin_amdgcn_mfma_f32_16x16x32_bf16(af, bf, acc[nf], 0, 0, 0); \
            }                                                                  \
        }                                                                      \
    } while (0)

// release: all waves done reading the buffer about to be overwritten
#define RELEASE_BAR                                                            \
    do {                                                                       \
        __builtin_amdgcn_sched_barrier(0);                                     \
        asm volatile("s_waitcnt lgkmcnt(0)" ::: "memory");                     \
        __builtin_amdgcn_s_barrier();                                          \
        __builtin_amdgcn_sched_barrier(0);                                     \
    } while (0)

    // issue first stage immediately
    STAGE(0, 0);

    // ---- epilogue operand PREFETCH (hidden under first-stage wait) ----
    const int n_e  = n0 + (tid >> 3);
    const int hc_e = bx * 8 + (tid & 7);
    const size_t ch_e = (size_t)n_e * 1024 + hc_e;
    const float c_pf = cbuf[ch_e];
    ushort xa_pf[4];
    if (XAF == 1) {
        const ushort* xp = xab_t + (size_t)n_e * FH + hc_e;
        xa_pf[0] = xp[0]; xa_pf[1] = xp[1024];
        xa_pf[2] = xp[2048]; xa_pf[3] = xp[3072];
    }
    uint4 p2_pf[8];
#pragma unroll
    for (int q = 0; q < 4; ++q) {
        const ushort* pp = P2 + ((size_t)n_e * FH + q * 1024 + hc_e) * 16;
        p2_pf[q * 2]     = *(const uint4*)pp;
        p2_pf[q * 2 + 1] = *(const uint4*)(pp + 8);
    }
    uint4 ab_pf0, ab_pf1;
    {
        const ushort* ap = Ab16 + ch_e * 16;
        ab_pf0 = *(const uint4*)ap;
        ab_pf1 = *(const uint4*)(ap + 8);
    }

    if (bid < 128) qk_zero[bid * 256 + tid] = 0.f;

    if (tid < 32) {   // softmax(qk/32): sum QB buckets, then exp-normalize
        const float* q = qk_cur + (n0 + tid) * 16;
        float4 s4[4];
#pragma unroll
        for (int q4 = 0; q4 < 4; ++q4) s4[q4] = ((const float4*)q)[q4];
#pragma unroll
        for (int bkt = 1; bkt < QB; ++bkt) {
            const float4* qb = (const float4*)(q + bkt * 2048);
#pragma unroll
            for (int q4 = 0; q4 < 4; ++q4) {
                float4 v = qb[q4];
                s4[q4].x += v.x; s4[q4].y += v.y; s4[q4].z += v.z; s4[q4].w += v.w;
            }
        }
        float s[16];
#pragma unroll
        for (int q4 = 0; q4 < 4; ++q4) {
            s[q4*4+0] = s4[q4].x; s[q4*4+1] = s4[q4].y;
            s[q4*4+2] = s4[q4].z; s[q4*4+3] = s4[q4].w;
        }
        float m = -1e30f;
#pragma unroll
        for (int k = 0; k < 16; ++k) { s[k] *= 0.03125f; m = fmaxf(m, s[k]); }
        float sum = 0.f;
#pragma unroll
        for (int k = 0; k < 16; ++k) { s[k] = __expf(s[k] - m); sum += s[k]; }
        float inv = __builtin_amdgcn_rcpf(sum);
#pragma unroll
        for (int k = 0; k < 16; ++k) wLDS[tid * 16 + k] = s[k] * inv;
    }

    float4v acc[2];
    acc[0] = (float4v){0.f, 0.f, 0.f, 0.f};
    acc[1] = (float4v){0.f, 0.f, 0.f, 0.f};

    // pin all prologue loads before the full drain so loop vmcnt counts are exact
    __builtin_amdgcn_sched_barrier(0);
    __syncthreads();    // full drain: stage0 + prefetch + softmax loads done

    if (XAF == 1) {
        // counted-vmcnt pipeline, NK=4; buffers alternate 0,1,0,1
        STAGE(1, 1);                    // 8 loads in flight (S1 -> buf1)
        COMPUTE(0);                     // kc=0 from buf0
        RELEASE_BAR;                    // buf0 free
        STAGE(0, 2);                    // S2 -> buf0; 16 in flight
        __builtin_amdgcn_sched_barrier(0);
        asm volatile("s_waitcnt vmcnt(8)" ::: "memory");   // S1 done
        __builtin_amdgcn_s_barrier();
        __builtin_amdgcn_sched_barrier(0);
        COMPUTE(1);                     // kc=1 from buf1
        RELEASE_BAR;                    // buf1 free
        STAGE(1, 3);                    // S3 -> buf1
        __builtin_amdgcn_sched_barrier(0);
        asm volatile("s_waitcnt vmcnt(8)" ::: "memory");   // S2 done
        __builtin_amdgcn_s_barrier();
        __builtin_amdgcn_sched_barrier(0);
        COMPUTE(0);                     // kc=2 from buf0
        __builtin_amdgcn_sched_barrier(0);
        asm volatile("s_waitcnt vmcnt(0)" ::: "memory");   // S3 done
        __builtin_amdgcn_s_barrier();
        __builtin_amdgcn_sched_barrier(0);
        COMPUTE(1);                     // kc=3 from buf1
    } else {
        int buf = 0;
#pragma unroll 1
        for (int kc = 0; kc < 8; ++kc) {
            if (kc + 1 < 8) STAGE(buf ^ 1, kc + 1);
            COMPUTE(buf);
            __syncthreads();
            buf ^= 1;
        }
    }
#undef STAGE
#undef COMPUTE
#undef RELEASE_BAR

    // combine K-halves via LDS
#pragma unroll
    for (int nf = 0; nf < 2; ++nf)
#pragma unroll
        for (int jj = 0; jj < 4; ++jj)
            accL[(kh * 32 + mh * 16 + g * 4 + jj) * 33 + nf * 16 + lr] = acc[nf][jj];
    __syncthreads();

    // ---- epilogue: thread = one (n, hc) cell, operands already in regs ----
    const int n_l = tid >> 3, hcl = tid & 7;
    const int n = n_e;
    const int hc = hc_e;

    float wv_[16];
#pragma unroll
    for (int k = 0; k < 16; ++k) wv_[k] = wLDS[n_l * 16 + k];

    float val[4];
#pragma unroll
    for (int q = 0; q < 4; ++q) {
        const int cq = q * 8 + hcl;
        float v = accL[n_l * 33 + cq] + accL[(32 + n_l) * 33 + cq]
                + bias[q * 1024 + hc];
        if (XAF == 1) v += b2f(xa_pf[q]);
        union { uint4 v[2]; ushort us[16]; } pv;
        pv.v[0] = p2_pf[q * 2];
        pv.v[1] = p2_pf[q * 2 + 1];
#pragma unroll
        for (int k = 0; k < 16; ++k) v += wv_[k] * b2f(pv.us[k]);
        val[q] = v;
    }

    float cn = sigm(val[1]) * c_pf + sigm(val[0]) * tanh_fast(val[3]);
    float hv = sigm(val[2]) * tanh_fast(cn);
    cbuf[ch_e] = cn;
    out_t[(size_t)n * (TT * HD) + hc] = hv;
    hnext[ch_e] = f2b(hv);

    // qk partials: p[k] = hv * A[n][hc][k], reduced over 8 hcl lanes
    union { uint4 v[2]; ushort us[16]; } av;
    av.v[0] = ab_pf0;
    av.v[1] = ab_pf1;
    float vv[16];
#pragma unroll
    for (int k = 0; k < 16; ++k) vv[k] = hv * b2f(av.us[k]);
    {
        bool hi = (hcl & 1);
#pragma unroll
        for (int q = 0; q < 8; ++q) {
            float send = hi ? vv[q] : vv[q + 8];
            float recv = __shfl_xor(send, 1);
            vv[q] = (hi ? vv[q + 8] : vv[q]) + recv;
        }
        hi = (hcl & 2);
#pragma unroll
        for (int q = 0; q < 4; ++q) {
            float send = hi ? vv[q] : vv[q + 4];
            float recv = __shfl_xor(send, 2);
            vv[q] = (hi ? vv[q + 4] : vv[q]) + recv;
        }
        hi = (hcl & 4);
#pragma unroll
        for (int q = 0; q < 2; ++q) {
            float send = hi ? vv[q] : vv[q + 2];
            float recv = __shfl_xor(send, 4);
            vv[q] = (hi ? vv[q + 2] : vv[q]) + recv;
        }
    }
    const int kbase = ((hcl & 1) << 3) | ((hcl & 2) << 1) | ((hcl & 4) >> 1);
    float* qdst = qk_next + (bx & (QB - 1)) * 2048 + n * 16;
    atomicAdd(qdst + kbase,     vv[0]);
    atomicAdd(qdst + kbase + 1, vv[1]);
}

// ---------------------------------------------------------------------------
extern "C" void kernel_launch(void* const* d_in, const int* in_sizes, int n_in,
                              void* d_out, int out_size, void* d_ws, size_t ws_size,
                              hipStream_t stream) {
    const float* x     = (const float*)d_in[0];
    const float* A     = (const float*)d_in[1];
    const float* Wx    = (const float*)d_in[2];
    const float* Wh    = (const float*)d_in[3];
    const float* Wattn = (const float*)d_in[4];
    const float* b     = (const float*)d_in[5];
    float* out = (float*)d_out;

    ushort* WT   = (ushort*)d_ws;                          // 3 x 8.39 MB
    ushort* WxT  = WT;
    ushort* WhT  = WT + (size_t)FH * 1024;
    ushort* WatT = WT + (size_t)2 * FH * 1024;
    ushort* Ab16 = WT + (size_t)3 * FH * 1024;             // 4.19 MB
    ushort* hb   = Ab16 + (size_t)NB * HD * 16;            // 2 x 0.26 MB
    float*  cb   = (float*)(hb + (size_t)2 * NB * HD);     // 0.52 MB
    float*  qk   = cb + (size_t)NB * HD;                   // 3 x 128 KB
    ushort* P2   = (ushort*)(qk + 3 * QSLOT);              // 16.78 MB
    ushort* tail = P2 + (size_t)NB * FH * 16;

    const size_t base  = (size_t)((char*)tail - (char*)d_ws);
    const size_t xasz  = (size_t)TT * NB * FH * 2;         // 134.2 MB
    const size_t xbsz  = (size_t)NB * TT * HD * 2;         // 33.55 MB

    build_wt<<<dim3(48, 64), 256, 0, stream>>>(Wx, Wh, Wattn, WT);
    init_kernel<<<NB, 256, 0, stream>>>(A, cb, hb, Ab16, qk, qk + QSLOT);
    p_gemm<<<dim3(16, 32), 256, 0, stream>>>(Ab16, WatT, P2);

    if (ws_size >= base + xasz) {
        ushort* xab = tail;
        if (ws_size >= base + xasz + xbsz) {
            // bf16-A path (round-11/13 winner): slabs fit per-XCD L2
            ushort* xb = tail + xasz / 2;
            cvt_x<<<8192, 256, 0, stream>>>(x, xb);
            xa_gemm3<1><<<4096, 256, 0, stream>>>(nullptr, xb, WxT, xab);
        } else {
            xa_gemm3<0><<<4096, 256, 0, stream>>>(x, nullptr, WxT, xab);
        }
        for (int t = 0; t < TT; ++t) {
            const ushort* hc = hb + (size_t)(t & 1) * NB * HD;
            ushort* hn       = hb + (size_t)((t + 1) & 1) * NB * HD;
            const float* qc  = qk + (size_t)(t % 3) * QSLOT;
            float* qn        = qk + (size_t)((t + 1) % 3) * QSLOT;
            float* qz        = qk + (size_t)((t + 2) % 3) * QSLOT;
            step_kernel<1><<<512, 256, 0, stream>>>(
                hc, hn, nullptr, xab + (size_t)t * NB * FH, WxT, WhT, P2, Ab16,
                b, cb, qc, qn, qz, out + (size_t)t * HD);
        }
    } else {
        ushort* xb = tail;
        cvt_x<<<8192, 256, 0, stream>>>(x, xb);
        for (int t = 0; t < TT; ++t) {
            const ushort* hc = hb + (size_t)(t & 1) * NB * HD;
            ushort* hn       = hb + (size_t)((t + 1) & 1) * NB * HD;
            const float* qc  = qk + (size_t)(t % 3) * QSLOT;
            float* qn        = qk + (size_t)((t + 1) % 3) * QSLOT;
            float* qz        = qk + (size_t)((t + 2) % 3) * QSLOT;
            step_kernel<0><<<512, 256, 0, stream>>>(
                hc, hn, xb + (size_t)t * HD, nullptr, WxT, WhT, P2, Ab16,
                b, cb, qc, qn, qz, out + (size_t)t * HD);
        }
    }
}

// Round 16
// 1649.894 us; speedup vs baseline: 1.0205x; 1.0205x over previous
//
#include <hip/hip_runtime.h>
#include <math.h>

#define NB 128
#define TT 128
#define HD 1024
#define FH 4096
#define QB 16            // qk contention-spread buckets
#define QSLOT (QB * 2048)

typedef __attribute__((ext_vector_type(8))) short short8v;
typedef __attribute__((ext_vector_type(4))) float float4v;

__device__ __forceinline__ ushort f2b(float f) {
    union { float f; unsigned u; } v; v.f = f;
    unsigned r = (v.u + 0x7fffu + ((v.u >> 16) & 1u)) >> 16;
    return (ushort)r;
}
__device__ __forceinline__ float b2f(ushort u) {
    union { unsigned u; float f; } v; v.u = ((unsigned)u) << 16;
    return v.f;
}
__device__ __forceinline__ float sigm(float x) {
    return __builtin_amdgcn_rcpf(1.f + __expf(-x));
}
__device__ __forceinline__ float tanh_fast(float x) {
    return 1.f - 2.f * __builtin_amdgcn_rcpf(1.f + __expf(2.f * x));
}
__device__ __forceinline__ void gll16(const void* g, void* l) {
    __builtin_amdgcn_global_load_lds(
        (const __attribute__((address_space(1))) void*)g,
        (__attribute__((address_space(3))) void*)l,
        16, 0, 0);
}
// XOR chunk swizzle within a 16-chunk (256B) row; involution in low 3 bits.
__device__ __forceinline__ int swz(int c, int r) {
    return (c & 8) | ((c & 7) ^ (r & 7));
}

// ---------------------------------------------------------------------------
// x fp32 -> bf16 ([N][T][D] preserved)
__global__ __launch_bounds__(256) void cvt_x(const float* __restrict__ x,
                                             ushort* __restrict__ xb) {
    size_t i = (size_t)blockIdx.x * 256 + threadIdx.x;
    const float4* p = (const float4*)x + i * 2;
    float4 va = p[0], vb = p[1];
    union { ushort u[8]; uint4 v; } o;
    o.u[0] = f2b(va.x); o.u[1] = f2b(va.y); o.u[2] = f2b(va.z); o.u[3] = f2b(va.w);
    o.u[4] = f2b(vb.x); o.u[5] = f2b(vb.y); o.u[6] = f2b(vb.z); o.u[7] = f2b(vb.w);
    ((uint4*)xb)[i] = o.v;
}

// ---------------------------------------------------------------------------
// WT layout: [WxT (4096x1024)] [WhT (4096x1024)] [WatT (4096x1024)], bf16.
__global__ __launch_bounds__(256) void build_wt(const float* __restrict__ Wx,
                                                const float* __restrict__ Wh,
                                                const float* __restrict__ Wattn,
                                                ushort* __restrict__ WT) {
    __shared__ ushort Ls[64][65];
    int k0 = blockIdx.x * 64, n0 = blockIdx.y * 64;
    const float* W; int m;
    if (k0 < 1024)      { W = Wx;    m = 0; }
    else if (k0 < 2048) { W = Wh;    m = 1; }
    else                { W = Wattn; m = 2; }
    const int kk0 = k0 - m * 1024;
    ushort* dstm = WT + (size_t)m * FH * 1024;
    int t = threadIdx.x;
    int cc = t & 63, r4 = t >> 6;
#pragma unroll
    for (int i = 0; i < 16; ++i) {
        int r = i * 4 + r4;
        Ls[r][cc] = f2b(W[(size_t)(kk0 + r) * FH + n0 + cc]);
    }
    __syncthreads();
#pragma unroll
    for (int i = 0; i < 16; ++i) {
        int nn = i * 4 + r4;
        dstm[(size_t)(n0 + nn) * 1024 + kk0 + cc] = Ls[cc][nn];
    }
}

// ---------------------------------------------------------------------------
// init: h0=c0=meanpool(A); Ab16 = bf16(A); qk0 bucket0 = sum_h h0*A,
// buckets 1..15 zero; qk1 all zero.
__global__ __launch_bounds__(256) void init_kernel(
    const float* __restrict__ Aflat, float* __restrict__ cbuf,
    ushort* __restrict__ h0buf, ushort* __restrict__ Ab16,
    float* __restrict__ qk0, float* __restrict__ qk1)
{
    __shared__ float red[4][16];
    const int n = blockIdx.x, tid = threadIdx.x;
    const int wv = tid >> 6, l = tid & 63;
    float p[16];
#pragma unroll
    for (int k = 0; k < 16; ++k) p[k] = 0.f;
#pragma unroll
    for (int u = 0; u < 4; ++u) {
        const int h = tid + u * 256;
        const size_t idx = (size_t)n * 1024 + h;
        const float4* a4 = (const float4*)(Aflat + idx * 16);
        float ar[16];
#pragma unroll
        for (int q = 0; q < 4; ++q) {
            float4 v = a4[q];
            ar[q*4+0]=v.x; ar[q*4+1]=v.y; ar[q*4+2]=v.z; ar[q*4+3]=v.w;
        }
        union { ushort us[16]; uint4 v[2]; } ob;
#pragma unroll
        for (int k = 0; k < 16; ++k) ob.us[k] = f2b(ar[k]);
        uint4* dst = (uint4*)(Ab16 + idx * 16);
        dst[0] = ob.v[0]; dst[1] = ob.v[1];

        float s = 0.f;
#pragma unroll
        for (int k = 0; k < 16; ++k) s += ar[k];
        float hv = s * 0.0625f;
        cbuf[idx] = hv;
        h0buf[idx] = f2b(hv);
#pragma unroll
        for (int k = 0; k < 16; ++k) p[k] += hv * ar[k];
    }
#pragma unroll
    for (int k = 0; k < 16; ++k) {
        float v = p[k];
        v += __shfl_xor(v, 32); v += __shfl_xor(v, 16); v += __shfl_xor(v, 8);
        v += __shfl_xor(v, 4);  v += __shfl_xor(v, 2);  v += __shfl_xor(v, 1);
        p[k] = v;
    }
    if (l == 0) {
#pragma unroll
        for (int k = 0; k < 16; ++k) red[wv][k] = p[k];
    }
    __syncthreads();
    if (tid < 16) {
        float val = red[0][tid] + red[1][tid] + red[2][tid] + red[3][tid];
#pragma unroll
        for (int bkt = 0; bkt < QB; ++bkt) {
            qk0[bkt * 2048 + n * 16 + tid] = (bkt == 0) ? val : 0.f;
            qk1[bkt * 2048 + n * 16 + tid] = 0.f;
        }
    }
}

// ---------------------------------------------------------------------------
// P2[n][j][k] = sum_h A[n][h][k] * Wattn[h][j]; 4-n batched per block.
__global__ __launch_bounds__(256) void p_gemm(
    const ushort* __restrict__ Ab16,    // [128][1024][16]
    const ushort* __restrict__ WatT,    // [4096][1024]
    ushort* __restrict__ P2)            // [128][4096][16] bf16
{
    __shared__ ushort ALDS[4 * 16 * 72];
    __shared__ ushort Bs[256 * 64];
    const int tid = threadIdx.x;
    const int wv = tid >> 6, l = tid & 63;
    const int lr = l & 15, g = l >> 4;
    const int jt = blockIdx.x, n0 = blockIdx.y * 4;
    const int snn = tid >> 6, shl = tid & 63;

    float4v acc[4][4];
#pragma unroll
    for (int i = 0; i < 4; ++i)
#pragma unroll
        for (int j = 0; j < 4; ++j) acc[i][j] = (float4v){0.f, 0.f, 0.f, 0.f};

#pragma unroll 1
    for (int kc = 0; kc < 16; ++kc) {
        __syncthreads();
        {
            const ushort* src = Ab16 + ((size_t)(n0 + snn) * 1024 + kc * 64 + shl) * 16;
            union { uint4 v[2]; ushort us[16]; } iv;
            iv.v[0] = *(const uint4*)src;
            iv.v[1] = *(const uint4*)(src + 8);
#pragma unroll
            for (int k = 0; k < 16; ++k)
                ALDS[(snn * 16 + k) * 72 + shl] = iv.us[k];
        }
#pragma unroll
        for (int i = 0; i < 8; ++i) {
            int s = i * 256 + tid;
            int r = s >> 3, c = (s & 7) ^ (r & 7);
            gll16(WatT + (size_t)(jt * 256 + r) * 1024 + kc * 64 + c * 8,
                  &Bs[s * 8]);
        }
        __syncthreads();
#pragma unroll
        for (int sub = 0; sub < 2; ++sub) {
            short8v af[4], bf[4];
#pragma unroll
            for (int nn = 0; nn < 4; ++nn)
                af[nn] = *(const short8v*)&ALDS[(nn * 16 + lr) * 72 + sub * 32 + g * 8];
#pragma unroll
            for (int nf = 0; nf < 4; ++nf) {
                int rb = wv * 64 + nf * 16 + lr;
                bf[nf] = *(const short8v*)&Bs[rb * 64 + (((sub * 4 + g) ^ (rb & 7)) * 8)];
            }
#pragma unroll
            for (int nn = 0; nn < 4; ++nn)
#pragma unroll
                for (int nf = 0; nf < 4; ++nf)
                    acc[nn][nf] = __builtin_amdgcn_mfma_f32_16x16x32_bf16(
                        af[nn], bf[nf], acc[nn][nf], 0, 0, 0);
        }
    }

#pragma unroll
    for (int nn = 0; nn < 4; ++nn)
#pragma unroll
        for (int nf = 0; nf < 4; ++nf) {
            const int j = jt * 256 + wv * 64 + nf * 16 + lr;
            union { ushort u[4]; uint2 v; } o;
#pragma unroll
            for (int jj = 0; jj < 4; ++jj) o.u[jj] = f2b(acc[nn][nf][jj]);
            *(uint2*)&P2[((size_t)(n0 + nn) * FH + j) * 16 + g * 4] = o.v;
        }
}

// ---------------------------------------------------------------------------
// XA[t][n][j] = x[n,t,:] @ Wx.  16384 x 1024 x 4096, BK=64 dbuf, 2 blocks/CU.
// B16A=1: A staged via gll16 from pre-converted xb (bf16 slabs fit L2 —
// rounds 11/13/15: 175-179 us / FETCH 164 MB vs fp32's 241 us / 295 MB).
// XCD-chunked bid swizzle: each XCD owns 16 A-slabs, sweeps 32 ntiles.
template <int B16A>
__global__ __launch_bounds__(256) void xa_gemm3(
    const float* __restrict__ x,        // [128][128][1024] fp32 (B16A=0)
    const ushort* __restrict__ xb,      // same, bf16 (B16A=1)
    const ushort* __restrict__ WxT,     // [4096][1024]
    ushort* __restrict__ xab)           // [128t][128n][4096]
{
    __shared__ ushort As[2][128 * 64];
    __shared__ ushort Bs[2][128 * 64];
    const int tid = threadIdx.x;
    const int w = tid >> 6, l = tid & 63;
    const int wm = w >> 1, wn = w & 1;
    const int lr = l & 15, g = l >> 4;

    const int bid = blockIdx.x;
    const int xcd = bid & 7, ii = bid >> 3;
    const int mt = xcd * 16 + (ii & 15);
    const int n0 = (ii >> 4) * 128;

    const float*  Ax  = x  + (size_t)mt * 128 * 1024;
    const ushort* Axb = xb + (size_t)mt * 128 * 1024;
    const ushort* Bb  = WxT + (size_t)n0 * 1024;

#define STAGEA(b, kf)                                                          \
    do {                                                                       \
        if (B16A) {                                                            \
            _Pragma("unroll")                                                  \
            for (int i = 0; i < 4; ++i) {                                      \
                int s = i * 256 + tid;                                         \
                int r = s >> 3, c = s & 7;                                     \
                gll16(Axb + (size_t)r * 1024 + (kf) + (c ^ (r & 7)) * 8,       \
                      &As[b][s * 8]);                                          \
            }                                                                  \
        } else {                                                               \
            _Pragma("unroll")                                                  \
            for (int i = 0; i < 4; ++i) {                                      \
                int u = i * 256 + tid;                                         \
                int r = u >> 3, c = u & 7;                                     \
                const float* s = Ax + (size_t)r * 1024 + (kf) + c * 8;         \
                float4 v0 = *(const float4*)s;                                 \
                float4 v1 = *(const float4*)(s + 4);                           \
                union { ushort us[8]; uint4 v; } o;                            \
                o.us[0]=f2b(v0.x); o.us[1]=f2b(v0.y); o.us[2]=f2b(v0.z);       \
                o.us[3]=f2b(v0.w); o.us[4]=f2b(v1.x); o.us[5]=f2b(v1.y);       \
                o.us[6]=f2b(v1.z); o.us[7]=f2b(v1.w);                          \
                *(uint4*)&As[b][(r * 8 + (c ^ (r & 7))) * 8] = o.v;            \
            }                                                                  \
        }                                                                      \
    } while (0)
#define STAGEB(b, kf)                                                          \
    do {                                                                       \
        _Pragma("unroll")                                                      \
        for (int s2 = 0; s2 < 4; ++s2) {                                       \
            int s = s2 * 256 + tid;                                            \
            int r = s >> 3, c = s & 7;                                         \
            gll16(Bb + (size_t)r * 1024 + (kf) + (c ^ (r & 7)) * 8,            \
                  &Bs[b][s * 8]);                                              \
        }                                                                      \
    } while (0)

    float4v acc[4][4];
#pragma unroll
    for (int i = 0; i < 4; ++i)
#pragma unroll
        for (int j = 0; j < 4; ++j) acc[i][j] = (float4v){0.f, 0.f, 0.f, 0.f};

    STAGEA(0, 0);
    STAGEB(0, 0);
    __syncthreads();
    int buf = 0;
#pragma unroll 1
    for (int kc = 0; kc < 16; ++kc) {
        if (kc < 15) { STAGEA(buf ^ 1, (kc + 1) * 64); STAGEB(buf ^ 1, (kc + 1) * 64); }
        const ushort* Ab = As[buf];
        const ushort* Bbuf = Bs[buf];
#pragma unroll
        for (int sub = 0; sub < 2; ++sub) {
            short8v af[4], bf[4];
#pragma unroll
            for (int mf = 0; mf < 4; ++mf) {
                int ra = wm * 64 + mf * 16 + lr;
                af[mf] = *(const short8v*)&Ab[ra * 64 + (((sub * 4 + g) ^ (ra & 7)) * 8)];
            }
#pragma unroll
            for (int nf = 0; nf < 4; ++nf) {
                int rb = wn * 64 + nf * 16 + lr;
                bf[nf] = *(const short8v*)&Bbuf[rb * 64 + (((sub * 4 + g) ^ (rb & 7)) * 8)];
            }
#pragma unroll
            for (int mf = 0; mf < 4; ++mf)
#pragma unroll
                for (int nf = 0; nf < 4; ++nf)
                    acc[mf][nf] = __builtin_amdgcn_mfma_f32_16x16x32_bf16(
                        af[mf], bf[nf], acc[mf][nf], 0, 0, 0);
        }
        __syncthreads();
        buf ^= 1;
    }
#undef STAGEA
#undef STAGEB

#pragma unroll
    for (int mf = 0; mf < 4; ++mf)
#pragma unroll
        for (int nf = 0; nf < 4; ++nf) {
            const int col = n0 + wn * 64 + nf * 16 + lr;
#pragma unroll
            for (int j = 0; j < 4; ++j) {
                const int rl = wm * 64 + mf * 16 + g * 4 + j;
                xab[((size_t)rl * NB + mt) * FH + col] = f2b(acc[mf][nf][j]);
            }
        }
}

// ---------------------------------------------------------------------------
// Per-step kernel (round-13 best: simple dbuf loop + epilogue operand
// prefetch). XAF=1: K=1024 (h @ WhT), 4 K-iters. XAF=0: K=2048, 8 K-iters.
// 512 blocks (2/CU), 256 thr = 4 waves (2 mh x 2 kh); 32n x 32j per block.
template <int XAF>
__global__ __launch_bounds__(256) void step_kernel(
    const ushort* __restrict__ hcur,    // [128][1024] bf16
    ushort* __restrict__ hnext,
    const ushort* __restrict__ xb_t,    // XAF=0: + t*HD, row stride TT*HD
    const ushort* __restrict__ xab_t,   // XAF=1: + t*NB*FH
    const ushort* __restrict__ WxT,     // [4096][1024]
    const ushort* __restrict__ WhT,     // [4096][1024]
    const ushort* __restrict__ P2,      // [128][4096][16]
    const ushort* __restrict__ Ab16,    // [128][1024][16]
    const float* __restrict__ bias,
    float* __restrict__ cbuf,
    const float* __restrict__ qk_cur,   // [QB][2048]
    float* __restrict__ qk_next,
    float* __restrict__ qk_zero,
    float* __restrict__ out_t)          // + t*HD, row stride TT*HD
{
    __shared__ ushort AS[16384];
    __shared__ ushort BS[16384];
    __shared__ float accL[2 * 32 * 33];
    __shared__ float wLDS[32 * 16];

    const int tid = threadIdx.x;
    const int w = tid >> 6, l = tid & 63;
    const int mh = w & 1, kh = w >> 1;
    const int lr = l & 15, g = l >> 4;

    // XCD-chunked swizzle
    const int bid = blockIdx.x;
    const int xcd = bid & 7, ii = bid >> 3;
    const int bx = xcd * 16 + (ii & 15);
    const int my = ii >> 4;
    const int n0 = my * 32;

#define STAGE(b, kc)                                                           \
    do {                                                                       \
        _Pragma("unroll")                                                      \
        for (int i = 0; i < 4; ++i) {                                          \
            int u = i * 256 + tid;                                             \
            int skh = u >> 9, rem = u & 511;                                   \
            int r = rem >> 4, c = rem & 15;                                    \
            int lc = swz(c, r);                                                \
            const ushort* src;                                                 \
            if (XAF == 1)                                                      \
                src = hcur + (size_t)(n0 + r) * 1024 + skh * 512               \
                      + (kc) * 128 + lc * 8;                                   \
            else                                                               \
                src = skh                                                      \
                    ? hcur + (size_t)(n0 + r) * 1024 + (kc) * 128 + lc * 8     \
                    : xb_t + (size_t)(n0 + r) * (TT * HD) + (kc) * 128 + lc * 8;\
            gll16(src, AS + (((b) * 2 + skh) * 512 + rem) * 8);                \
        }                                                                      \
        _Pragma("unroll")                                                      \
        for (int i = 0; i < 4; ++i) {                                          \
            int u = i * 256 + tid;                                             \
            int skh = u >> 9, rem = u & 511;                                   \
            int r = rem >> 4, c = rem & 15;                                    \
            int lc = swz(c, r);                                                \
            int jg = (r >> 3) * 1024 + bx * 8 + (r & 7);                       \
            const ushort* src;                                                 \
            if (XAF == 1)                                                      \
                src = WhT + (size_t)jg * 1024 + skh * 512 + (kc) * 128 + lc * 8;\
            else                                                               \
                src = (skh ? WhT : WxT) + (size_t)jg * 1024                    \
                      + (kc) * 128 + lc * 8;                                   \
            gll16(src, BS + (((b) * 2 + skh) * 512 + rem) * 8);                \
        }                                                                      \
    } while (0)

    // issue first stage immediately
    STAGE(0, 0);

    // ---- epilogue operand PREFETCH (hidden under first-stage wait) ----
    const int n_e  = n0 + (tid >> 3);
    const int hc_e = bx * 8 + (tid & 7);
    const size_t ch_e = (size_t)n_e * 1024 + hc_e;
    const float c_pf = cbuf[ch_e];
    ushort xa_pf[4];
    if (XAF == 1) {
        const ushort* xp = xab_t + (size_t)n_e * FH + hc_e;
        xa_pf[0] = xp[0]; xa_pf[1] = xp[1024];
        xa_pf[2] = xp[2048]; xa_pf[3] = xp[3072];
    }
    uint4 p2_pf[8];
#pragma unroll
    for (int q = 0; q < 4; ++q) {
        const ushort* pp = P2 + ((size_t)n_e * FH + q * 1024 + hc_e) * 16;
        p2_pf[q * 2]     = *(const uint4*)pp;
        p2_pf[q * 2 + 1] = *(const uint4*)(pp + 8);
    }
    uint4 ab_pf0, ab_pf1;
    {
        const ushort* ap = Ab16 + ch_e * 16;
        ab_pf0 = *(const uint4*)ap;
        ab_pf1 = *(const uint4*)(ap + 8);
    }

    if (bid < 128) qk_zero[bid * 256 + tid] = 0.f;

    if (tid < 32) {   // softmax(qk/32): sum QB buckets, then exp-normalize
        const float* q = qk_cur + (n0 + tid) * 16;
        float4 s4[4];
#pragma unroll
        for (int q4 = 0; q4 < 4; ++q4) s4[q4] = ((const float4*)q)[q4];
#pragma unroll
        for (int bkt = 1; bkt < QB; ++bkt) {
            const float4* qb = (const float4*)(q + bkt * 2048);
#pragma unroll
            for (int q4 = 0; q4 < 4; ++q4) {
                float4 v = qb[q4];
                s4[q4].x += v.x; s4[q4].y += v.y; s4[q4].z += v.z; s4[q4].w += v.w;
            }
        }
        float s[16];
#pragma unroll
        for (int q4 = 0; q4 < 4; ++q4) {
            s[q4*4+0] = s4[q4].x; s[q4*4+1] = s4[q4].y;
            s[q4*4+2] = s4[q4].z; s[q4*4+3] = s4[q4].w;
        }
        float m = -1e30f;
#pragma unroll
        for (int k = 0; k < 16; ++k) { s[k] *= 0.03125f; m = fmaxf(m, s[k]); }
        float sum = 0.f;
#pragma unroll
        for (int k = 0; k < 16; ++k) { s[k] = __expf(s[k] - m); sum += s[k]; }
        float inv = __builtin_amdgcn_rcpf(sum);
#pragma unroll
        for (int k = 0; k < 16; ++k) wLDS[tid * 16 + k] = s[k] * inv;
    }

    float4v acc[2];
    acc[0] = (float4v){0.f, 0.f, 0.f, 0.f};
    acc[1] = (float4v){0.f, 0.f, 0.f, 0.f};

    const int NK = (XAF == 1) ? 4 : 8;
    __syncthreads();
    int buf = 0;
#pragma unroll 1
    for (int kc = 0; kc < NK; ++kc) {
        if (kc + 1 < NK) STAGE(buf ^ 1, kc + 1);
        const int base = (buf * 2 + kh) * 512;
        const int ra = mh * 16 + lr;
#pragma unroll
        for (int ks = 0; ks < 4; ++ks) {
            const int c = ks * 4 + g;
            short8v af = *(const short8v*)&AS[(base + ra * 16 + swz(c, ra)) * 8];
#pragma unroll
            for (int nf = 0; nf < 2; ++nf) {
                const int rb = nf * 16 + lr;
                short8v bf = *(const short8v*)&BS[(base + rb * 16 + swz(c, rb)) * 8];
                acc[nf] = __builtin_amdgcn_mfma_f32_16x16x32_bf16(af, bf, acc[nf], 0, 0, 0);
            }
        }
        __syncthreads();
        buf ^= 1;
    }
#undef STAGE

    // combine K-halves via LDS
#pragma unroll
    for (int nf = 0; nf < 2; ++nf)
#pragma unroll
        for (int jj = 0; jj < 4; ++jj)
            accL[(kh * 32 + mh * 16 + g * 4 + jj) * 33 + nf * 16 + lr] = acc[nf][jj];
    __syncthreads();

    // ---- epilogue: thread = one (n, hc) cell, operands already in regs ----
    const int n_l = tid >> 3, hcl = tid & 7;
    const int n = n_e;
    const int hc = hc_e;

    float wv_[16];
#pragma unroll
    for (int k = 0; k < 16; ++k) wv_[k] = wLDS[n_l * 16 + k];

    float val[4];
#pragma unroll
    for (int q = 0; q < 4; ++q) {
        const int cq = q * 8 + hcl;
        float v = accL[n_l * 33 + cq] + accL[(32 + n_l) * 33 + cq]
                + bias[q * 1024 + hc];
        if (XAF == 1) v += b2f(xa_pf[q]);
        union { uint4 v[2]; ushort us[16]; } pv;
        pv.v[0] = p2_pf[q * 2];
        pv.v[1] = p2_pf[q * 2 + 1];
#pragma unroll
        for (int k = 0; k < 16; ++k) v += wv_[k] * b2f(pv.us[k]);
        val[q] = v;
    }

    float cn = sigm(val[1]) * c_pf + sigm(val[0]) * tanh_fast(val[3]);
    float hv = sigm(val[2]) * tanh_fast(cn);
    cbuf[ch_e] = cn;
    out_t[(size_t)n * (TT * HD) + hc] = hv;
    hnext[ch_e] = f2b(hv);

    // qk partials: p[k] = hv * A[n][hc][k], reduced over 8 hcl lanes
    union { uint4 v[2]; ushort us[16]; } av;
    av.v[0] = ab_pf0;
    av.v[1] = ab_pf1;
    float vv[16];
#pragma unroll
    for (int k = 0; k < 16; ++k) vv[k] = hv * b2f(av.us[k]);
    {
        bool hi = (hcl & 1);
#pragma unroll
        for (int q = 0; q < 8; ++q) {
            float send = hi ? vv[q] : vv[q + 8];
            float recv = __shfl_xor(send, 1);
            vv[q] = (hi ? vv[q + 8] : vv[q]) + recv;
        }
        hi = (hcl & 2);
#pragma unroll
        for (int q = 0; q < 4; ++q) {
            float send = hi ? vv[q] : vv[q + 4];
            float recv = __shfl_xor(send, 2);
            vv[q] = (hi ? vv[q + 4] : vv[q]) + recv;
        }
        hi = (hcl & 4);
#pragma unroll
        for (int q = 0; q < 2; ++q) {
            float send = hi ? vv[q] : vv[q + 2];
            float recv = __shfl_xor(send, 4);
            vv[q] = (hi ? vv[q + 2] : vv[q]) + recv;
        }
    }
    const int kbase = ((hcl & 1) << 3) | ((hcl & 2) << 1) | ((hcl & 4) >> 1);
    float* qdst = qk_next + (bx & (QB - 1)) * 2048 + n * 16;
    atomicAdd(qdst + kbase,     vv[0]);
    atomicAdd(qdst + kbase + 1, vv[1]);
}

// ---------------------------------------------------------------------------
extern "C" void kernel_launch(void* const* d_in, const int* in_sizes, int n_in,
                              void* d_out, int out_size, void* d_ws, size_t ws_size,
                              hipStream_t stream) {
    const float* x     = (const float*)d_in[0];
    const float* A     = (const float*)d_in[1];
    const float* Wx    = (const float*)d_in[2];
    const float* Wh    = (const float*)d_in[3];
    const float* Wattn = (const float*)d_in[4];
    const float* b     = (const float*)d_in[5];
    float* out = (float*)d_out;

    ushort* WT   = (ushort*)d_ws;                          // 3 x 8.39 MB
    ushort* WxT  = WT;
    ushort* WhT  = WT + (size_t)FH * 1024;
    ushort* WatT = WT + (size_t)2 * FH * 1024;
    ushort* Ab16 = WT + (size_t)3 * FH * 1024;             // 4.19 MB
    ushort* hb   = Ab16 + (size_t)NB * HD * 16;            // 2 x 0.26 MB
    float*  cb   = (float*)(hb + (size_t)2 * NB * HD);     // 0.52 MB
    float*  qk   = cb + (size_t)NB * HD;                   // 3 x 128 KB
    ushort* P2   = (ushort*)(qk + 3 * QSLOT);              // 16.78 MB
    ushort* tail = P2 + (size_t)NB * FH * 16;

    const size_t base  = (size_t)((char*)tail - (char*)d_ws);
    const size_t xasz  = (size_t)TT * NB * FH * 2;         // 134.2 MB
    const size_t xbsz  = (size_t)NB * TT * HD * 2;         // 33.55 MB

    build_wt<<<dim3(48, 64), 256, 0, stream>>>(Wx, Wh, Wattn, WT);
    init_kernel<<<NB, 256, 0, stream>>>(A, cb, hb, Ab16, qk, qk + QSLOT);
    p_gemm<<<dim3(16, 32), 256, 0, stream>>>(Ab16, WatT, P2);

    if (ws_size >= base + xasz) {
        ushort* xab = tail;
        if (ws_size >= base + xasz + xbsz) {
            // bf16-A path (round-11/13 winner): slabs fit per-XCD L2
            ushort* xb = tail + xasz / 2;
            cvt_x<<<8192, 256, 0, stream>>>(x, xb);
            xa_gemm3<1><<<4096, 256, 0, stream>>>(nullptr, xb, WxT, xab);
        } else {
            xa_gemm3<0><<<4096, 256, 0, stream>>>(x, nullptr, WxT, xab);
        }
        for (int t = 0; t < TT; ++t) {
            const ushort* hc = hb + (size_t)(t & 1) * NB * HD;
            ushort* hn       = hb + (size_t)((t + 1) & 1) * NB * HD;
            const float* qc  = qk + (size_t)(t % 3) * QSLOT;
            float* qn        = qk + (size_t)((t + 1) % 3) * QSLOT;
            float* qz        = qk + (size_t)((t + 2) % 3) * QSLOT;
            step_kernel<1><<<512, 256, 0, stream>>>(
                hc, hn, nullptr, xab + (size_t)t * NB * FH, WxT, WhT, P2, Ab16,
                b, cb, qc, qn, qz, out + (size_t)t * HD);
        }
    } else {
        ushort* xb = tail;
        cvt_x<<<8192, 256, 0, stream>>>(x, xb);
        for (int t = 0; t < TT; ++t) {
            const ushort* hc = hb + (size_t)(t & 1) * NB * HD;
            ushort* hn       = hb + (size_t)((t + 1) & 1) * NB * HD;
            const float* qc  = qk + (size_t)(t % 3) * QSLOT;
            float* qn        = qk + (size_t)((t + 1) % 3) * QSLOT;
            float* qz        = qk + (size_t)((t + 2) % 3) * QSLOT;
            step_kernel<0><<<512, 256, 0, stream>>>(
                hc, hn, xb + (size_t)t * HD, nullptr, WxT, WhT, P2, Ab16,
                b, cb, qc, qn, qz, out + (size_t)t * HD);
        }
    }
}